// Round 1
// baseline (992.330 us; speedup 1.0000x reference)
//
#include <hip/hip_runtime.h>
#include <cstdint>
#include <cstddef>

// Problem constants (match reference)
static constexpr int cNA = 100000, cNP = 200000, cNU = 5000;
static constexpr int cDA = 128, cDP = 128, cDU = 64, cH = 32;
static constexpr int cEW = 2000000, cEP = 200000;

// ---------------------------------------------------------------------------
// prep: build combined per-node-type weight matrices and bias vectors.
//  W_A [128][33] : cols 0..31 = wr_Ws, col 32 = rw_Wd @ rw_ad
//  W_P [128][66] : cols 0..31 = pi_Ws, 32..63 = rw_Ws, 64 = wr_Wd@wr_ad, 65 = rp_Wd@rp_ad
//  W_U [ 64][33] : cols 0..31 = rp_Ws, col 32 = pi_Wd @ pi_ad
//  bias[0..31]=rw_b, bias[32..63]=0.5*(wr_b+rp_b), bias[64..95]=pi_b
// ---------------------------------------------------------------------------
__global__ void prep_kernel(
    const float* __restrict__ wr_Ws, const float* __restrict__ wr_Wd,
    const float* __restrict__ wr_ad, const float* __restrict__ wr_b,
    const float* __restrict__ pi_Ws, const float* __restrict__ pi_Wd,
    const float* __restrict__ pi_ad, const float* __restrict__ pi_b,
    const float* __restrict__ rw_Ws, const float* __restrict__ rw_Wd,
    const float* __restrict__ rw_ad, const float* __restrict__ rw_b,
    const float* __restrict__ rp_Ws, const float* __restrict__ rp_Wd,
    const float* __restrict__ rp_ad, const float* __restrict__ rp_b,
    float* __restrict__ W_A, float* __restrict__ W_P, float* __restrict__ W_U,
    float* __restrict__ bias)
{
    int k = threadIdx.x;  // 128 threads, 1 block
    if (k < 128) {
        for (int c = 0; c < 32; ++c) W_A[k * 33 + c] = wr_Ws[k * 32 + c];
        float dv = 0.f;
        for (int j = 0; j < 32; ++j) dv += rw_Wd[k * 32 + j] * rw_ad[j];
        W_A[k * 33 + 32] = dv;

        for (int c = 0; c < 32; ++c) W_P[k * 66 + c] = pi_Ws[k * 32 + c];
        for (int c = 0; c < 32; ++c) W_P[k * 66 + 32 + c] = rw_Ws[k * 32 + c];
        float d1 = 0.f, d2 = 0.f;
        for (int j = 0; j < 32; ++j) {
            d1 += wr_Wd[k * 32 + j] * wr_ad[j];
            d2 += rp_Wd[k * 32 + j] * rp_ad[j];
        }
        W_P[k * 66 + 64] = d1;
        W_P[k * 66 + 65] = d2;
    }
    if (k < 64) {
        for (int c = 0; c < 32; ++c) W_U[k * 33 + c] = rp_Ws[k * 32 + c];
        float dv = 0.f;
        for (int j = 0; j < 32; ++j) dv += pi_Wd[k * 32 + j] * pi_ad[j];
        W_U[k * 33 + 32] = dv;
    }
    if (k < 32) {
        bias[k]      = rw_b[k];
        bias[32 + k] = 0.5f * (wr_b[k] + rp_b[k]);
        bias[64 + k] = pi_b[k];
    }
}

// ---------------------------------------------------------------------------
// proj: per node type, one pass over x computing hs blocks (+ their s scalars)
// and d scalar columns. One thread per node; W loads are wave-uniform (SGPR).
// ---------------------------------------------------------------------------
template <int D, int NHS, int ND>
__global__ __launch_bounds__(256) void proj_kernel(
    const float* __restrict__ x, const float* __restrict__ W, int N,
    const float* __restrict__ as0, const float* __restrict__ as1,
    float* __restrict__ hs0, float* __restrict__ s0,
    float* __restrict__ hs1, float* __restrict__ s1,
    float* __restrict__ dd0, float* __restrict__ dd1)
{
    constexpr int C = NHS * 32 + ND;
    int n = blockIdx.x * blockDim.x + threadIdx.x;
    if (n >= N) return;
    float acc[C];
#pragma unroll
    for (int c = 0; c < C; ++c) acc[c] = 0.f;
    const float* xr = x + (size_t)n * D;
    for (int k = 0; k < D; k += 4) {
        float4 xv = *reinterpret_cast<const float4*>(xr + k);
        const float* w = W + (size_t)k * C;
#pragma unroll
        for (int c = 0; c < C; ++c) acc[c] += xv.x * w[c];
#pragma unroll
        for (int c = 0; c < C; ++c) acc[c] += xv.y * w[C + c];
#pragma unroll
        for (int c = 0; c < C; ++c) acc[c] += xv.z * w[2 * C + c];
#pragma unroll
        for (int c = 0; c < C; ++c) acc[c] += xv.w * w[3 * C + c];
    }
    {
        float sv = 0.f;
#pragma unroll
        for (int c = 0; c < 32; ++c) sv += acc[c] * as0[c];
        s0[n] = sv;
        float4* o = reinterpret_cast<float4*>(hs0 + (size_t)n * 32);
#pragma unroll
        for (int i = 0; i < 8; ++i)
            o[i] = make_float4(acc[4 * i], acc[4 * i + 1], acc[4 * i + 2], acc[4 * i + 3]);
    }
    if constexpr (NHS == 2) {
        float sv = 0.f;
#pragma unroll
        for (int c = 0; c < 32; ++c) sv += acc[32 + c] * as1[c];
        s1[n] = sv;
        float4* o = reinterpret_cast<float4*>(hs1 + (size_t)n * 32);
#pragma unroll
        for (int i = 0; i < 8; ++i)
            o[i] = make_float4(acc[32 + 4 * i], acc[32 + 4 * i + 1],
                               acc[32 + 4 * i + 2], acc[32 + 4 * i + 3]);
    }
    dd0[n] = acc[NHS * 32];
    if constexpr (ND == 2) dd1[n] = acc[NHS * 32 + 1];
}

// ---------------------------------------------------------------------------
// CSR build for the 2M-edge writes relation (both directions in one pass).
// hist: count[dst]++ (counters are L2-resident: 800KB/400KB)
// ---------------------------------------------------------------------------
__global__ __launch_bounds__(256) void hist_kernel(
    const int* __restrict__ wsrc, const int* __restrict__ wdst,
    int* __restrict__ cntA, int* __restrict__ cntP, int E)
{
    int i = blockIdx.x * blockDim.x + threadIdx.x;
    if (i >= E) return;
    atomicAdd(&cntP[wdst[i]], 1);
    atomicAdd(&cntA[wsrc[i]], 1);
}

// Two-level exclusive scan: A) per-block (2048-elem chunk) sums,
// B) serial scan over block sums (<=128), C) in-block scan + offset.
__global__ __launch_bounds__(256) void scanA_kernel(
    const int* __restrict__ cnt, int* __restrict__ bsum, int n)
{
    int t = threadIdx.x;
    int i0 = blockIdx.x * 2048 + t * 8;
    int s = 0;
#pragma unroll
    for (int j = 0; j < 8; ++j) {
        int i = i0 + j;
        s += (i < n) ? cnt[i] : 0;
    }
    for (int off = 1; off < 64; off <<= 1) s += __shfl_xor(s, off);
    __shared__ int ws_[4];
    int lane = t & 63, w = t >> 6;
    if (lane == 0) ws_[w] = s;
    __syncthreads();
    if (t == 0) bsum[blockIdx.x] = ws_[0] + ws_[1] + ws_[2] + ws_[3];
}

__global__ void scanB_kernel(int* __restrict__ bsum, int nb)
{
    // 1 thread; nb <= 128
    int run = 0;
    for (int i = 0; i < nb; ++i) { int v = bsum[i]; bsum[i] = run; run += v; }
}

__global__ __launch_bounds__(256) void scanC_kernel(
    const int* __restrict__ cnt, const int* __restrict__ bsum,
    int* __restrict__ rowstart, int* __restrict__ cursor, int n)
{
    int t = threadIdx.x;
    int i0 = blockIdx.x * 2048 + t * 8;
    int vals[8];
    int s = 0;
#pragma unroll
    for (int j = 0; j < 8; ++j) {
        int i = i0 + j;
        vals[j] = (i < n) ? cnt[i] : 0;
        s += vals[j];
    }
    int lane = t & 63, w = t >> 6;
    int incl = s;
    for (int off = 1; off < 64; off <<= 1) {
        int u = __shfl_up(incl, off);
        if (lane >= off) incl += u;
    }
    __shared__ int wsum[4];
    if (lane == 63) wsum[w] = incl;
    __syncthreads();
    int woff = 0;
    for (int k = 0; k < w; ++k) woff += wsum[k];
    int excl = incl - s + woff + bsum[blockIdx.x];
#pragma unroll
    for (int j = 0; j < 8; ++j) {
        int i = i0 + j;
        if (i < n) { rowstart[i] = excl; cursor[i] = excl; }
        excl += vals[j];
    }
}

// scatter: place src index of every edge into its dst's contiguous range,
// for both edge directions in one pass. Cursor atomics are L2-resident.
__global__ __launch_bounds__(256) void scatter_kernel(
    const int* __restrict__ wsrc, const int* __restrict__ wdst,
    int* __restrict__ curP, int* __restrict__ sortedW,
    int* __restrict__ curA, int* __restrict__ sortedR, int E)
{
    int i = blockIdx.x * blockDim.x + threadIdx.x;
    if (i >= E) return;
    int s = wsrc[i], d = wdst[i];
    int p = atomicAdd(&curP[d], 1);
    sortedW[p] = s;
    int q = atomicAdd(&curA[s], 1);
    sortedR[q] = d;
}

// ---------------------------------------------------------------------------
// gather: one 32-lane group per dst node (lane = channel). Walk the dst's
// contiguous src list, recompute ex = exp(leaky_relu(s[src]+d[dst])),
// accumulate ex*hs[src][lane] in registers, write acc row + den ONCE.
// Replaces 32 scattered atomicAdds/edge with one coalesced store/node.
// ---------------------------------------------------------------------------
__global__ __launch_bounds__(256) void gather_kernel(
    const int* __restrict__ rowstart, const int* __restrict__ cnt,
    const int* __restrict__ esrc,
    const float* __restrict__ sval, const float* __restrict__ dval,
    const float* __restrict__ hs,
    float* __restrict__ acc, float* __restrict__ den, int N)
{
    int g = blockIdx.x * blockDim.x + threadIdx.x;
    int d = g >> 5, lane = g & 31;
    if (d >= N) return;
    int beg = rowstart[d];
    int deg = cnt[d];
    float dd = dval[d];
    float a = 0.f, dn = 0.f;
    for (int t0 = 0; t0 < deg; t0 += 32) {
        int rem = deg - t0;
        int m = rem < 32 ? rem : 32;
        int myS = 0;
        float mySv = 0.f;
        if (lane < m) {
            myS = esrc[beg + t0 + lane];
            mySv = sval[myS];
        }
        for (int j = 0; j < m; ++j) {
            int s = __shfl(myS, j, 32);
            float sv = __shfl(mySv, j, 32);
            float e = sv + dd;
            e = e >= 0.f ? e : 0.2f * e;
            float ex = __expf(e);
            dn += ex;
            a += ex * hs[(size_t)s * 32 + lane];
        }
    }
    acc[(size_t)d * 32 + lane] = a;
    if (lane == 0) den[d] = dn;
}

// ---------------------------------------------------------------------------
// edge: atomic path, kept only for the small pub relations (200K edges).
// ---------------------------------------------------------------------------
__global__ __launch_bounds__(256) void edge_kernel(
    const int* __restrict__ src, const int* __restrict__ dst,
    const float* __restrict__ s, const float* __restrict__ d,
    const float* __restrict__ hs, float* __restrict__ den,
    float* __restrict__ acc, int E)
{
    int g = blockIdx.x * blockDim.x + threadIdx.x;
    int e = g >> 5;
    if (e >= E) return;
    int h = g & 31;
    int si = src[e], di = dst[e];
    float ev = s[si] + d[di];
    ev = ev >= 0.f ? ev : 0.2f * ev;
    float ex = __expf(ev);
    if (h == 0) atomicAdd(den + di, ex);
    atomicAdd(acc + (size_t)di * 32 + h, ex * hs[(size_t)si * 32 + h]);
}

// ---------------------------------------------------------------------------
// final: combine relations, /den (0 if no in-edges), +bias, relu, @lin_W+lin_b
// ---------------------------------------------------------------------------
__global__ __launch_bounds__(256) void final_kernel(
    const float* __restrict__ acc0, const float* __restrict__ den0,
    const float* __restrict__ acc1, const float* __restrict__ den1,
    const float* __restrict__ bias, float scale,
    const float* __restrict__ linW, const float* __restrict__ linb,
    float* __restrict__ out, int N)
{
    int n = blockIdx.x * blockDim.x + threadIdx.x;
    if (n >= N) return;
    float v[32];
    {
        float dn = den0[n];
        float inv = dn > 0.f ? 1.f / dn : 0.f;
        const float4* a0 = reinterpret_cast<const float4*>(acc0 + (size_t)n * 32);
#pragma unroll
        for (int i = 0; i < 8; ++i) {
            float4 t = a0[i];
            v[4 * i] = t.x * inv; v[4 * i + 1] = t.y * inv;
            v[4 * i + 2] = t.z * inv; v[4 * i + 3] = t.w * inv;
        }
    }
    if (acc1 != nullptr) {
        float dn = den1[n];
        float inv = dn > 0.f ? 1.f / dn : 0.f;
        const float4* a1 = reinterpret_cast<const float4*>(acc1 + (size_t)n * 32);
#pragma unroll
        for (int i = 0; i < 8; ++i) {
            float4 t = a1[i];
            v[4 * i] += t.x * inv; v[4 * i + 1] += t.y * inv;
            v[4 * i + 2] += t.z * inv; v[4 * i + 3] += t.w * inv;
        }
    }
#pragma unroll
    for (int h = 0; h < 32; ++h) {
        float t = scale * v[h] + bias[h];
        v[h] = t > 0.f ? t : 0.f;
    }
    float y[32];
#pragma unroll
    for (int j = 0; j < 32; ++j) y[j] = linb[j];
#pragma unroll
    for (int h = 0; h < 32; ++h) {
        float vh = v[h];
#pragma unroll
        for (int j = 0; j < 32; ++j) y[j] += vh * linW[h * 32 + j];
    }
    float4* o = reinterpret_cast<float4*>(out + (size_t)n * 32);
#pragma unroll
    for (int i = 0; i < 8; ++i)
        o[i] = make_float4(y[4 * i], y[4 * i + 1], y[4 * i + 2], y[4 * i + 3]);
}

extern "C" void kernel_launch(void* const* d_in, const int* in_sizes, int n_in,
                              void* d_out, int out_size, void* d_ws, size_t ws_size,
                              hipStream_t stream)
{
    const float* x_author = (const float*)d_in[0];
    const float* x_paper  = (const float*)d_in[1];
    const float* x_unit   = (const float*)d_in[2];
    const int* writes_src = (const int*)d_in[3];
    const int* writes_dst = (const int*)d_in[4];
    const int* pub_src    = (const int*)d_in[5];
    const int* pub_dst    = (const int*)d_in[6];
    const float* wr_Ws = (const float*)d_in[7];
    const float* wr_Wd = (const float*)d_in[8];
    const float* wr_as = (const float*)d_in[9];
    const float* wr_ad = (const float*)d_in[10];
    const float* wr_b  = (const float*)d_in[11];
    const float* pi_Ws = (const float*)d_in[12];
    const float* pi_Wd = (const float*)d_in[13];
    const float* pi_as = (const float*)d_in[14];
    const float* pi_ad = (const float*)d_in[15];
    const float* pi_b  = (const float*)d_in[16];
    const float* rw_Ws = (const float*)d_in[17];
    const float* rw_Wd = (const float*)d_in[18];
    const float* rw_as = (const float*)d_in[19];
    const float* rw_ad = (const float*)d_in[20];
    const float* rw_b  = (const float*)d_in[21];
    const float* rp_Ws = (const float*)d_in[22];
    const float* rp_Wd = (const float*)d_in[23];
    const float* rp_as = (const float*)d_in[24];
    const float* rp_ad = (const float*)d_in[25];
    const float* rp_b  = (const float*)d_in[26];
    const float* lin_W = (const float*)d_in[27];
    const float* lin_b = (const float*)d_in[28];
    float* out = (float*)d_out;
    float* ws = (float*)d_ws;

    // workspace layout (float offsets, padded to 64)
    size_t off = 0;
    auto A = [&](size_t nf) { size_t o = off; off += (nf + 63) & ~(size_t)63; return o; };
    size_t oWA   = A(128 * 33);
    size_t oWP   = A(128 * 66);
    size_t oWU   = A(64 * 33);
    size_t oBias = A(96);
    size_t oHsWr = A((size_t)cNA * 32);
    size_t oHsPi = A((size_t)cNP * 32);
    size_t oHsRw = A((size_t)cNP * 32);
    size_t oHsRp = A((size_t)cNU * 32);
    size_t oSwr  = A(cNA);
    size_t oSpi  = A(cNP);
    size_t oSrw  = A(cNP);
    size_t oSrp  = A(cNU);
    size_t oDwr  = A(cNP);
    size_t oDrp  = A(cNP);
    size_t oDpi  = A(cNU);
    size_t oDrw  = A(cNA);
    // CSR-path buffers (written each launch; no zeroing needed)
    size_t oAccWr = A((size_t)cNP * 32);
    size_t oDenWr = A(cNP);
    size_t oAccRw = A((size_t)cNA * 32);
    size_t oDenRw = A(cNA);
    size_t oRsP   = A(cNP);
    size_t oCurP  = A(cNP);
    size_t oRsA   = A(cNA);
    size_t oCurA  = A(cNA);
    size_t oBsP   = A(128);
    size_t oBsA   = A(128);
    size_t oSortW = A(cEW);   // author idx grouped by paper
    size_t oSortR = A(cEW);   // paper idx grouped by author
    // zero-region: atomic-path accumulators (pub relations) + histograms
    size_t zs = off;
    size_t oCntP  = A(cNP);
    size_t oCntA  = A(cNA);
    size_t oDenRp = A(cNP);
    size_t oDenPi = A(cNU);
    size_t oAccRp = A((size_t)cNP * 32);
    size_t oAccPi = A((size_t)cNU * 32);
    size_t ze = off;

    hipMemsetAsync((void*)(ws + zs), 0, (ze - zs) * sizeof(float), stream);

    prep_kernel<<<1, 128, 0, stream>>>(
        wr_Ws, wr_Wd, wr_ad, wr_b,
        pi_Ws, pi_Wd, pi_ad, pi_b,
        rw_Ws, rw_Wd, rw_ad, rw_b,
        rp_Ws, rp_Wd, rp_ad, rp_b,
        ws + oWA, ws + oWP, ws + oWU, ws + oBias);

    // ---- CSR build for writes relation (both directions) ----
    {
        int* cntP = (int*)(ws + oCntP);
        int* cntA = (int*)(ws + oCntA);
        int* rsP  = (int*)(ws + oRsP);
        int* curP = (int*)(ws + oCurP);
        int* rsA  = (int*)(ws + oRsA);
        int* curA = (int*)(ws + oCurA);
        int* bsP  = (int*)(ws + oBsP);
        int* bsA  = (int*)(ws + oBsA);
        int* sortW = (int*)(ws + oSortW);
        int* sortR = (int*)(ws + oSortR);

        int eb = (cEW + 255) / 256;
        hist_kernel<<<eb, 256, 0, stream>>>(writes_src, writes_dst, cntA, cntP, cEW);

        int nbP = (cNP + 2047) / 2048;
        int nbA = (cNA + 2047) / 2048;
        scanA_kernel<<<nbP, 256, 0, stream>>>(cntP, bsP, cNP);
        scanA_kernel<<<nbA, 256, 0, stream>>>(cntA, bsA, cNA);
        scanB_kernel<<<1, 1, 0, stream>>>(bsP, nbP);
        scanB_kernel<<<1, 1, 0, stream>>>(bsA, nbA);
        scanC_kernel<<<nbP, 256, 0, stream>>>(cntP, bsP, rsP, curP, cNP);
        scanC_kernel<<<nbA, 256, 0, stream>>>(cntA, bsA, rsA, curA, cNA);

        scatter_kernel<<<eb, 256, 0, stream>>>(writes_src, writes_dst,
                                               curP, sortW, curA, sortR, cEW);
    }

    proj_kernel<128, 1, 1><<<(cNA + 255) / 256, 256, 0, stream>>>(
        x_author, ws + oWA, cNA, wr_as, nullptr,
        ws + oHsWr, ws + oSwr, nullptr, nullptr, ws + oDrw, nullptr);
    proj_kernel<128, 2, 2><<<(cNP + 255) / 256, 256, 0, stream>>>(
        x_paper, ws + oWP, cNP, pi_as, rw_as,
        ws + oHsPi, ws + oSpi, ws + oHsRw, ws + oSrw, ws + oDwr, ws + oDrp);
    proj_kernel<64, 1, 1><<<(cNU + 255) / 256, 256, 0, stream>>>(
        x_unit, ws + oWU, cNU, rp_as, nullptr,
        ws + oHsRp, ws + oSrp, nullptr, nullptr, ws + oDpi, nullptr);

    // ---- writes relation: gather (register accumulation, coalesced store) ----
    // wr: author -> paper (CSR by paper, src lists contain authors)
    gather_kernel<<<((size_t)cNP * 32 + 255) / 256, 256, 0, stream>>>(
        (int*)(ws + oRsP), (int*)(ws + oCntP), (int*)(ws + oSortW),
        ws + oSwr, ws + oDwr, ws + oHsWr,
        ws + oAccWr, ws + oDenWr, cNP);
    // rw: paper -> author (CSR by author, src lists contain papers)
    gather_kernel<<<((size_t)cNA * 32 + 255) / 256, 256, 0, stream>>>(
        (int*)(ws + oRsA), (int*)(ws + oCntA), (int*)(ws + oSortR),
        ws + oSrw, ws + oDrw, ws + oHsRw,
        ws + oAccRw, ws + oDenRw, cNA);

    // ---- pub relations: atomic path (small: 200K edges) ----
    {
        int blocks = (int)(((long long)cEP * 32 + 255) / 256);
        // pi: paper -> unit (acc region 640KB, L2-resident)
        edge_kernel<<<blocks, 256, 0, stream>>>(
            pub_src, pub_dst, ws + oSpi, ws + oDpi, ws + oHsPi,
            ws + oDenPi, ws + oAccPi, cEP);
        // rp: unit -> paper
        edge_kernel<<<blocks, 256, 0, stream>>>(
            pub_dst, pub_src, ws + oSrp, ws + oDrp, ws + oHsRp,
            ws + oDenRp, ws + oAccRp, cEP);
    }

    // outputs: author, paper, unit (concatenated)
    final_kernel<<<(cNA + 255) / 256, 256, 0, stream>>>(
        ws + oAccRw, ws + oDenRw, nullptr, nullptr,
        ws + oBias + 0, 1.0f, lin_W, lin_b, out, cNA);
    final_kernel<<<(cNP + 255) / 256, 256, 0, stream>>>(
        ws + oAccWr, ws + oDenWr, ws + oAccRp, ws + oDenRp,
        ws + oBias + 32, 0.5f, lin_W, lin_b, out + (size_t)cNA * 32, cNP);
    final_kernel<<<(cNU + 255) / 256, 256, 0, stream>>>(
        ws + oAccPi, ws + oDenPi, nullptr, nullptr,
        ws + oBias + 64, 1.0f, lin_W, lin_b, out + (size_t)(cNA + cNP) * 32, cNU);
}